// Round 1
// baseline (134.621 us; speedup 1.0000x reference)
//
#include <hip/hip_runtime.h>
#include <hip/hip_bf16.h>
#include <math.h>

#define NN 512
#define RR 16
#define HH 16

// Block: 512 threads = 32 j-groups x 16 c-lanes.
//   lane c owns output column c (of H=16); group g walks j = g, g+32, ...
// Kernel 1: bk/bq (stage-1 einsums) -> att1 -> silu MLP -> att2 row (N x 1024) in ws.
// Kernel 2: S + right-term einsums + separable left-term -> att3 -> silu MLP -> out.

__global__ __launch_bounds__(512) void junmai_k1(
    const float* __restrict__ x,
    const float* __restrict__ W,     // (2,N,R,H)
    const float* __restrict__ W1,    // (16,256)
    const float* __restrict__ b1,    // (16,)
    const float* __restrict__ W2,    // (1024,16)
    float* __restrict__ att2)        // (N,1024) ws
{
    const int i   = blockIdx.x;
    const int tid = threadIdx.x;
    const int c   = tid & 15;
    const int g   = tid >> 4;        // 0..31

    __shared__ float s_red[32][16][6];   // [group][c][bk0..2,bq0..2]
    __shared__ float s_bkq[16][6];       // reduced bk/bq per c
    __shared__ float s_att[256];
    __shared__ float s_a1[16];

    const float xi0 = x[i*3+0];
    const float xi1 = x[i*3+1];
    const float xi2 = x[i*3+2];

    const float start = 0.006737946999085467f;      // exp(-5)
    const float step  = (1.0f - start) * (1.0f/15.0f);
    const float sb    = 0.125f * (1.0f - start);
    const float beta  = 1.0f / (sb * sb);

    const float* Kp = W;
    const float* Qp = W + NN*RR*HH;

    float ak0=0.f, ak1=0.f, ak2=0.f, aq0=0.f, aq1=0.f, aq2=0.f;

    for (int j = g; j < NN; j += 32) {
        float d0 = xi0 - x[j*3+0];
        float d1 = xi1 - x[j*3+1];
        float d2 = xi2 - x[j*3+2];
        float nsq = fmaf(d0,d0, fmaf(d1,d1, fmaf(d2,d2, 1e-6f)));
        float inv = 1.0f / nsq;
        float nrm = sqrtf(nsq);
        d0 *= inv; d1 *= inv; d2 *= inv;
        float cutv = 0.0f;
        if (nrm < 5.0f) cutv = 0.5f * (cosf(nrm * 0.6283185307179586f) + 1.0f);
        float en = __expf(-nrm);

        const float* kj = Kp + j*256 + c;
        const float* qj = Qp + j*256 + c;
        float tk = 0.f, tq = 0.f;
        #pragma unroll
        for (int r = 0; r < 16; ++r) {
            float m = fmaf(step, (float)r, start);
            float t = en - m;
            float e = __expf(-beta * t * t);
            tk = fmaf(e, kj[r*16], tk);
            tq = fmaf(e, qj[r*16], tq);
        }
        tk *= cutv; tq *= cutv;
        ak0 = fmaf(tk, d0, ak0); ak1 = fmaf(tk, d1, ak1); ak2 = fmaf(tk, d2, ak2);
        aq0 = fmaf(tq, d0, aq0); aq1 = fmaf(tq, d1, aq1); aq2 = fmaf(tq, d2, aq2);
    }

    s_red[g][c][0]=ak0; s_red[g][c][1]=ak1; s_red[g][c][2]=ak2;
    s_red[g][c][3]=aq0; s_red[g][c][4]=aq1; s_red[g][c][5]=aq2;
    __syncthreads();

    if (tid < 96) {                    // 16 c * 6 slots
        int cc = tid / 6, s = tid % 6;
        float acc = 0.f;
        #pragma unroll
        for (int gg = 0; gg < 32; ++gg) acc += s_red[gg][cc][s];
        s_bkq[cc][s] = acc;
    }
    __syncthreads();

    if (tid < 256) {                   // att1[h,g2] = sum_b bk[h,b]*bq[g2,b]
        int h = tid >> 4, g2 = tid & 15;
        s_att[tid] = s_bkq[h][0]*s_bkq[g2][3]
                   + s_bkq[h][1]*s_bkq[g2][4]
                   + s_bkq[h][2]*s_bkq[g2][5];
    }
    __syncthreads();

    if (tid < 16) {                    // z1 = att1 @ W1.T + b1 ; silu
        float z = b1[tid];
        const float* w1r = W1 + tid*256;
        for (int m = 0; m < 256; ++m) z = fmaf(s_att[m], w1r[m], z);
        s_a1[tid] = z / (1.0f + __expf(-z));
    }
    __syncthreads();

    {                                  // att2 row = a1 @ W2.T  (1024 outputs, 2/thread)
        float a[16];
        #pragma unroll
        for (int cc = 0; cc < 16; ++cc) a[cc] = s_a1[cc];
        #pragma unroll
        for (int oo = 0; oo < 2; ++oo) {
            int o = tid + oo*512;
            const float* w2r = W2 + o*16;
            float acc = 0.f;
            #pragma unroll
            for (int cc = 0; cc < 16; ++cc) acc = fmaf(a[cc], w2r[cc], acc);
            att2[i*1024 + o] = acc;
        }
    }
}

__global__ __launch_bounds__(512) void junmai_k2(
    const float* __restrict__ x,
    const float* __restrict__ att2,  // (N,1024)
    const float* __restrict__ W3,    // (16,256)
    const float* __restrict__ b3,    // (16,)
    const float* __restrict__ W4,    // (1,16)
    const float* __restrict__ b4,    // (1,)
    float* __restrict__ out)         // (N,1)
{
    const int i   = blockIdx.x;
    const int tid = threadIdx.x;
    const int c   = tid & 15;
    const int g   = tid >> 4;

    __shared__ float s_red[32][16][9];   // [group][c][bk2*3, bq2*3, S*3 (r=c)]
    __shared__ float s_acc[16][9];
    __shared__ float s_att[256];
    __shared__ float s_a1[16];

    const float xi0 = x[i*3+0];
    const float xi1 = x[i*3+1];
    const float xi2 = x[i*3+2];

    const float start = 0.006737946999085467f;
    const float step  = (1.0f - start) * (1.0f/15.0f);
    const float sb    = 0.125f * (1.0f - start);
    const float beta  = 1.0f / (sb * sb);

    float ak0=0.f, ak1=0.f, ak2=0.f, aq0=0.f, aq1=0.f, aq2=0.f;
    float as0=0.f, as1=0.f, as2=0.f;

    const float mc = fmaf(step, (float)c, start);   // means[c] for the S-accumulator

    for (int j = g; j < NN; j += 32) {
        float d0 = xi0 - x[j*3+0];
        float d1 = xi1 - x[j*3+1];
        float d2 = xi2 - x[j*3+2];
        float nsq = fmaf(d0,d0, fmaf(d1,d1, fmaf(d2,d2, 1e-6f)));
        float inv = 1.0f / nsq;
        float nrm = sqrtf(nsq);
        d0 *= inv; d1 *= inv; d2 *= inv;
        float cutv = 0.0f;
        if (nrm < 5.0f) cutv = 0.5f * (cosf(nrm * 0.6283185307179586f) + 1.0f);
        float en = __expf(-nrm);

        const float* rj = att2 + j*1024 + 512 + c;  // right_k at [r*16], right_q at [256+r*16]
        float tk = 0.f, tq = 0.f;
        #pragma unroll
        for (int r = 0; r < 16; ++r) {
            float m = fmaf(step, (float)r, start);
            float t = en - m;
            float e = __expf(-beta * t * t);
            tk = fmaf(e, rj[r*16],     tk);
            tq = fmaf(e, rj[256+r*16], tq);
        }
        tk *= cutv; tq *= cutv;
        float tc  = en - mc;
        float smc = cutv * __expf(-beta * tc * tc);

        ak0 = fmaf(tk, d0, ak0); ak1 = fmaf(tk, d1, ak1); ak2 = fmaf(tk, d2, ak2);
        aq0 = fmaf(tq, d0, aq0); aq1 = fmaf(tq, d1, aq1); aq2 = fmaf(tq, d2, aq2);
        as0 = fmaf(smc,d0, as0); as1 = fmaf(smc,d1, as1); as2 = fmaf(smc,d2, as2);
    }

    s_red[g][c][0]=ak0; s_red[g][c][1]=ak1; s_red[g][c][2]=ak2;
    s_red[g][c][3]=aq0; s_red[g][c][4]=aq1; s_red[g][c][5]=aq2;
    s_red[g][c][6]=as0; s_red[g][c][7]=as1; s_red[g][c][8]=as2;
    __syncthreads();

    if (tid < 144) {                   // 16 c * 9 slots
        int cc = tid / 9, s = tid % 9;
        float acc = 0.f;
        #pragma unroll
        for (int gg = 0; gg < 32; ++gg) acc += s_red[gg][cc][s];
        s_acc[cc][s] = acc;
    }
    __syncthreads();

    if (tid < 96) {                    // separable left-term: q(1)|cc(16)|b(3)
        int q  = (tid >= 48) ? 1 : 0;
        int u  = tid - q*48;
        int cc = u / 3, b = u % 3;
        const float* lrow = att2 + i*1024 + q*256 + cc;   // left_{k|q}[r*16+cc]
        float add = 0.f;
        #pragma unroll
        for (int r = 0; r < 16; ++r) add = fmaf(lrow[r*16], s_acc[r][6+b], add);
        s_acc[cc][q*3 + b] += add;     // slots 0..5 written, 6..8 read: disjoint
    }
    __syncthreads();

    if (tid < 256) {                   // att3
        int h = tid >> 4, g2 = tid & 15;
        s_att[tid] = s_acc[h][0]*s_acc[g2][3]
                   + s_acc[h][1]*s_acc[g2][4]
                   + s_acc[h][2]*s_acc[g2][5];
    }
    __syncthreads();

    if (tid < 16) {
        float z = b3[tid];
        const float* w3r = W3 + tid*256;
        for (int m = 0; m < 256; ++m) z = fmaf(s_att[m], w3r[m], z);
        s_a1[tid] = z / (1.0f + __expf(-z));
    }
    __syncthreads();

    if (tid == 0) {
        float acc = b4[0];
        #pragma unroll
        for (int cc = 0; cc < 16; ++cc) acc = fmaf(s_a1[cc], W4[cc], acc);
        out[i] = acc;
    }
}

extern "C" void kernel_launch(void* const* d_in, const int* in_sizes, int n_in,
                              void* d_out, int out_size, void* d_ws, size_t ws_size,
                              hipStream_t stream) {
    (void)in_sizes; (void)n_in; (void)out_size; (void)ws_size;
    const float* x  = (const float*)d_in[0];
    const float* W  = (const float*)d_in[1];
    const float* W1 = (const float*)d_in[2];
    const float* b1 = (const float*)d_in[3];
    const float* W2 = (const float*)d_in[4];
    const float* W3 = (const float*)d_in[5];
    const float* b3 = (const float*)d_in[6];
    const float* W4 = (const float*)d_in[7];
    const float* b4 = (const float*)d_in[8];
    float* att2 = (float*)d_ws;           // N*1024 f32 = 2 MB
    float* out  = (float*)d_out;

    junmai_k1<<<NN, 512, 0, stream>>>(x, W, W1, b1, W2, att2);
    junmai_k2<<<NN, 512, 0, stream>>>(x, att2, W3, b3, W4, b4, out);
}